// Round 18
// baseline (769.190 us; speedup 1.0000x reference)
//
#include <hip/hip_runtime.h>
#include <hip/hip_bf16.h>
#include <math.h>

#define NN 50000
#define EE 800000
#define FIN 128
#define HIDN 128
#define HD 32
#define FEATD 268
#define K1 288           // GEMM1 K padded to 9*32
#define KP1 296          // featsB LDS row stride (bf16 elems)
#define TE 32
#define TN2 64

typedef __bf16 bf16x8 __attribute__((ext_vector_type(8)));
typedef float  f32x4  __attribute__((ext_vector_type(4)));

#define MFMA(a, b, c) __builtin_amdgcn_mfma_f32_16x16x32_bf16((a), (b), (c), 0, 0, 0)

__device__ __forceinline__ float silu_f(float x) {
    const float e = __builtin_amdgcn_exp2f(-1.44269504088896f * x);
    return x * __builtin_amdgcn_rcpf(1.0f + e);
}

__device__ __forceinline__ __bf16 fbf(float x) {
    union { float f; unsigned u; } v; v.f = x;
    const unsigned r = (v.u + 0x7FFFu + ((v.u >> 16) & 1u)) >> 16;
    union { unsigned short s; __bf16 b; } o; o.s = (unsigned short)r;
    return o.b;
}

// Transpose + bf16-convert all weights into ws each launch (deterministic).
__global__ void wconv_kernel(const float* __restrict__ eW1, const float* __restrict__ eW2,
                             const float* __restrict__ cW1, const float* __restrict__ nW1,
                             const float* __restrict__ nW2,
                             __bf16* __restrict__ eW1t, __bf16* __restrict__ eW2t,
                             __bf16* __restrict__ cW1t, __bf16* __restrict__ nW1t,
                             __bf16* __restrict__ nW2t)
{
    const int i = blockIdx.x * 256 + threadIdx.x;
    if (i < 4 * 32 * K1) {
        const int hh = i / (32 * K1), rs = i % (32 * K1), d = rs / K1, k = rs % K1;
        const float v = (k < FEATD) ? eW1[(size_t)hh * FEATD * HD + (size_t)k * HD + d] : 0.f;
        eW1t[i] = (__bf16)v;
    }
    if (i < 4 * HD * HD) {
        const int hh = i / (HD * HD), rs = i % (HD * HD), d = rs / HD, k = rs % HD;
        eW2t[i] = (__bf16)eW2[(size_t)hh * HD * HD + (size_t)k * HD + d];
    }
    if (i < HIDN * HIDN) {
        const int o = i / HIDN, k = i % HIDN;
        cW1t[i] = (__bf16)cW1[(size_t)k * HIDN + o];
    }
    if (i < HIDN * (2 * FIN)) {
        const int o = i / (2 * FIN), k = i % (2 * FIN);
        nW1t[i] = (__bf16)nW1[(size_t)k * HIDN + o];
    }
    if (i < FIN * HIDN) {
        const int o = i / HIDN, k = i % HIDN;
        nW2t[i] = (__bf16)nW2[(size_t)k * FIN + o];
    }
}

// Convert h (f32 [NN][128]) -> bf16 in the LOWER 256B of each 512B h_out row.
__global__ __launch_bounds__(256) void hconv_kernel(const float* __restrict__ h,
                                                    float* __restrict__ houtbase)
{
    const int i = blockIdx.x * 256 + threadIdx.x;
    if (i >= NN * FIN / 8) return;
    const int row = i >> 4;
    const int c8  = i & 15;
    const float4* src = (const float4*)(h + (size_t)row * FIN + c8 * 8);
    float4 a = src[0], b = src[1];
    bf16x8 v = { fbf(a.x), fbf(a.y), fbf(a.z), fbf(a.w),
                 fbf(b.x), fbf(b.y), fbf(b.z), fbf(b.w) };
    *(bf16x8*)((char*)houtbase + (size_t)row * 512 + c8 * 16) = v;
}

// TE=32, 256 threads = 4 waves (wave = head). 3 barriers per tile:
// stage | GEMM1+GEMM2(same-wave hidB) + lnS | LN-norm | agg-atomics + GEMM3 + direct coord atomics.
__global__ __launch_bounds__(256) void edge_kernel(
    const float* __restrict__ coord,
    const int* __restrict__ ei,
    const __bf16* __restrict__ eW1t, const float* __restrict__ eb1,
    const __bf16* __restrict__ eW2t, const float* __restrict__ eb2,
    const float* __restrict__ ln_g, const float* __restrict__ ln_b,
    const __bf16* __restrict__ cW1t, const float* __restrict__ cb1,
    const float* __restrict__ cW2,
    float* __restrict__ houtbase, float* __restrict__ coord_out)
{
    __shared__ __align__(16) __bf16 featsB[TE][KP1];               // 18,944B (never aliased)
    __shared__ __align__(16) unsigned char smemB[4 * TE * 40 * 2]; // 10,240B: hidB -> efsB alias
    __shared__ float cdiff[TE][3];
    __shared__ int   rowlds[TE];
    __shared__ float lnS[TE][2];

    __bf16 (*efsB)[136] = (__bf16 (*)[136])smemB;

    const int t  = threadIdx.x;
    const int e0 = blockIdx.x * TE;

    if (t < TE) { lnS[t][0] = 0.f; lnS[t][1] = 0.f; }

    // ---------------- Phase 0: gather hB (bf16) + geometry into featsB ----------------
    {
        const int e = t >> 3;        // edge 0..31 (8 threads/edge)
        const int q = t & 7;
        const int r = ei[e0 + e];
        const int c = ei[EE + e0 + e];
        #pragma unroll
        for (int j = 0; j < 2; j++) {
            const int c16 = q + 8 * j;   // 16B-chunk index 0..15
            uint4 vr = *(const uint4*)((const char*)houtbase + (size_t)r * 512 + c16 * 16);
            *(uint4*)&featsB[e][c16 * 8] = vr;
            uint4 vc = *(const uint4*)((const char*)houtbase + (size_t)c * 512 + c16 * 16);
            *(uint4*)&featsB[e][FIN + c16 * 8] = vc;
        }
        if (q == 0) {
            rowlds[e] = r;
            const float cix = coord[(size_t)r*3+0], ciy = coord[(size_t)r*3+1], ciz = coord[(size_t)r*3+2];
            const float ckx = coord[(size_t)c*3+0], cky = coord[(size_t)c*3+1], ckz = coord[(size_t)c*3+2];
            const float dx = cix-ckx, dy = ciy-cky, dz = ciz-ckz;
            cdiff[e][0]=dx; cdiff[e][1]=dy; cdiff[e][2]=dz;
            const float radial = dx*dx + dy*dy + dz*dz;
            const float dist   = sqrtf(radial);
            const float dotv   = cix*ckx + ciy*cky + ciz*ckz;
            const float ia = 1.0f / (dist + 1e-8f);
            float ax = dx*ia, ay = dy*ia, az = dz*ia;
            const float cpx = ciy*ckz - ciz*cky;
            const float cpy = ciz*ckx - cix*ckz;
            const float cpz = cix*cky - ciy*ckx;
            const float cpn = sqrtf(cpx*cpx + cpy*cpy + cpz*cpz);
            const float ib = 1.0f / (cpn + 1e-8f);
            float bx = cpx*ib, by = cpy*ib, bz = cpz*ib;
            float cx = ay*bz - az*by;
            float cy = az*bx - ax*bz;
            float cz = ax*by - ay*bx;
            const float na = sqrtf(ax*ax + ay*ay + az*az);
            const float nb = sqrtf(bx*bx + by*by + bz*bz);
            const float nc = sqrtf(cx*cx + cy*cy + cz*cz);
            if (na < 1e-6f || nb < 1e-6f || nc < 1e-6f) {
                ax=1.f; bx=0.f; cx=0.f;
                ay=0.f; by=1.f; cy=0.f;
                az=0.f; bz=0.f; cz=1.f;
            }
            featsB[e][256]=fbf(radial); featsB[e][257]=fbf(dist); featsB[e][258]=fbf(dotv);
            featsB[e][259]=fbf(ax); featsB[e][260]=fbf(bx); featsB[e][261]=fbf(cx);
            featsB[e][262]=fbf(ay); featsB[e][263]=fbf(by); featsB[e][264]=fbf(cy);
            featsB[e][265]=fbf(az); featsB[e][266]=fbf(bz); featsB[e][267]=fbf(cz);
            #pragma unroll
            for (int k = FEATD; k < K1; k++) featsB[e][k] = (__bf16)0.f;
        }
    }
    __syncthreads();   // BAR1: featsB + init ready

    const int hh   = t >> 6;          // wave = head
    const int lane = t & 63;
    const int lr   = lane & 15;
    const int lg   = lane >> 4;
    __bf16* hidB = ((__bf16*)smemB) + hh * (TE * 40);

    const f32x4 z4 = { 0.f, 0.f, 0.f, 0.f };

    // ---------------- GEMM1 -> hidB (same wave) -> GEMM2 -> val regs + lnS ----------------
    float val[2][2][4];
    {
        __builtin_amdgcn_s_setprio(1);
        f32x4 acc[2][2];
        #pragma unroll
        for (int mti = 0; mti < 2; mti++) { acc[mti][0] = z4; acc[mti][1] = z4; }
        const __bf16* W1 = eW1t + (size_t)hh * 32 * K1;
        #pragma unroll
        for (int ks = 0; ks < 9; ks++) {
            const int kof = ks * 32 + lg * 8;
            bf16x8 b0 = *(const bf16x8*)(W1 + (size_t)lr * K1 + kof);
            bf16x8 b1 = *(const bf16x8*)(W1 + (size_t)(16 + lr) * K1 + kof);
            #pragma unroll
            for (int mti = 0; mti < 2; mti++) {
                bf16x8 a = *(const bf16x8*)(&featsB[mti * 16 + lr][kof]);
                acc[mti][0] = MFMA(a, b0, acc[mti][0]);
                acc[mti][1] = MFMA(a, b1, acc[mti][1]);
            }
        }
        __builtin_amdgcn_s_setprio(0);
        const float b1a = eb1[hh * HD + lr];
        const float b1b = eb1[hh * HD + 16 + lr];
        #pragma unroll
        for (int mti = 0; mti < 2; mti++) {
            #pragma unroll
            for (int r = 0; r < 4; r++) {
                const int erow = mti * 16 + lg * 4 + r;
                hidB[erow * 40 + lr]      = fbf(silu_f(acc[mti][0][r] + b1a));
                hidB[erow * 40 + 16 + lr] = fbf(silu_f(acc[mti][1][r] + b1b));
            }
        }
        // GEMM2 reads hidB written by the SAME wave -> compiler lgkmcnt, no barrier.
        f32x4 acc2[2][2];
        #pragma unroll
        for (int mti = 0; mti < 2; mti++) { acc2[mti][0] = z4; acc2[mti][1] = z4; }
        const __bf16* W2 = eW2t + (size_t)hh * HD * HD;
        const int kof2 = lg * 8;
        bf16x8 b20 = *(const bf16x8*)(W2 + (size_t)lr * HD + kof2);
        bf16x8 b21 = *(const bf16x8*)(W2 + (size_t)(16 + lr) * HD + kof2);
        __builtin_amdgcn_s_setprio(1);
        #pragma unroll
        for (int mti = 0; mti < 2; mti++) {
            bf16x8 a = *(const bf16x8*)(hidB + (mti * 16 + lr) * 40 + kof2);
            acc2[mti][0] = MFMA(a, b20, acc2[mti][0]);
            acc2[mti][1] = MFMA(a, b21, acc2[mti][1]);
        }
        __builtin_amdgcn_s_setprio(0);
        const float b2a = eb2[hh * HD + lr];
        const float b2b = eb2[hh * HD + 16 + lr];
        #pragma unroll
        for (int mti = 0; mti < 2; mti++) {
            #pragma unroll
            for (int r = 0; r < 4; r++) {
                val[mti][0][r] = acc2[mti][0][r] + b2a;
                val[mti][1][r] = acc2[mti][1][r] + b2b;
                float s  = val[mti][0][r] + val[mti][1][r];
                float s2 = val[mti][0][r]*val[mti][0][r] + val[mti][1][r]*val[mti][1][r];
                s  += __shfl_xor(s, 1);  s2 += __shfl_xor(s2, 1);
                s  += __shfl_xor(s, 2);  s2 += __shfl_xor(s2, 2);
                s  += __shfl_xor(s, 4);  s2 += __shfl_xor(s2, 4);
                s  += __shfl_xor(s, 8);  s2 += __shfl_xor(s2, 8);
                if (lr == 0) {
                    const int R = mti * 16 + lg * 4 + r;
                    atomicAdd(&lnS[R][0], s);
                    atomicAdd(&lnS[R][1], s2);
                }
            }
        }
    }
    __syncthreads();   // BAR2: lnS complete; all hidB reads done (efsB alias safe)

    // ---------------- LN normalize in registers -> efsB ----------------
    {
        const int c0 = hh * 32 + lr, c1 = c0 + 16;
        const float g0 = ln_g[c0], bl0 = ln_b[c0];
        const float g1 = ln_g[c1], bl1 = ln_b[c1];
        #pragma unroll
        for (int mti = 0; mti < 2; mti++) {
            #pragma unroll
            for (int r = 0; r < 4; r++) {
                const int R = mti * 16 + lg * 4 + r;
                const float mu   = lnS[R][0] * (1.f / 128.f);
                const float var  = lnS[R][1] * (1.f / 128.f) - mu * mu;
                const float rstd = rsqrtf(var + 1e-5f);
                efsB[R][c0] = fbf((val[mti][0][r] - mu) * rstd * g0 + bl0);
                efsB[R][c1] = fbf((val[mti][1][r] - mu) * rstd * g1 + bl1);
            }
        }
    }
    __syncthreads();   // BAR3: efsB ready (cross-wave)

    // ---------------- agg scatter FIRST (atomics overlap GEMM3) ----------------
    {
        const int p  = t & 63;
        const int gq = t >> 6;
        #pragma unroll
        for (int e2 = 0; e2 < 8; e2++) {
            const int ee = gq * 8 + e2;
            __hip_bfloat162 pk = *(__hip_bfloat162*)&efsB[ee][2 * p];
            __hip_bfloat162* addr = (__hip_bfloat162*)
                ((char*)houtbase + (size_t)rowlds[ee] * 512 + 256 + p * 4);
            unsafeAtomicAdd(addr, pk);
        }
    }

    // ---------------- GEMM3: efsB @ cW1t^T -> silu -> *cW2 -> partial w -> direct coord atomics ----------------
    {
        f32x4 acc3[2][2];
        #pragma unroll
        for (int mti = 0; mti < 2; mti++) { acc3[mti][0] = z4; acc3[mti][1] = z4; }
        const __bf16* W3 = cW1t + (size_t)hh * 32 * HIDN;
        __builtin_amdgcn_s_setprio(1);
        #pragma unroll
        for (int ks = 0; ks < 4; ks++) {
            const int kof = ks * 32 + lg * 8;
            bf16x8 b30 = *(const bf16x8*)(W3 + (size_t)lr * HIDN + kof);
            bf16x8 b31 = *(const bf16x8*)(W3 + (size_t)(16 + lr) * HIDN + kof);
            #pragma unroll
            for (int mti = 0; mti < 2; mti++) {
                bf16x8 a = *(const bf16x8*)(&efsB[mti * 16 + lr][kof]);
                acc3[mti][0] = MFMA(a, b30, acc3[mti][0]);
                acc3[mti][1] = MFMA(a, b31, acc3[mti][1]);
            }
        }
        __builtin_amdgcn_s_setprio(0);
        const int c0 = hh * 32 + lr, c1 = c0 + 16;
        const float cbA = cb1[c0], cbB = cb1[c1];
        const float cwA = cW2[c0], cwB = cW2[c1];
        float pe[8];
        #pragma unroll
        for (int mti = 0; mti < 2; mti++)
            #pragma unroll
            for (int r = 0; r < 4; r++)
                pe[mti * 4 + r] = silu_f(acc3[mti][0][r] + cbA) * cwA
                                + silu_f(acc3[mti][1][r] + cbB) * cwB;
        #pragma unroll
        for (int d = 1; d < 16; d <<= 1)
            #pragma unroll
            for (int i = 0; i < 8; i++) pe[i] += __shfl_xor(pe[i], d);
        // Each wave adds its own 32-column partial w directly (no wsum/BAR4).
        if (lr == 0) {
            #pragma unroll
            for (int mti = 0; mti < 2; mti++) {
                #pragma unroll
                for (int r = 0; r < 4; r++) {
                    const int ee = mti * 16 + lg * 4 + r;
                    const float we = pe[mti * 4 + r];
                    const int rn = rowlds[ee];
                    atomicAdd(&coord_out[(size_t)rn*3+0], cdiff[ee][0] * we);
                    atomicAdd(&coord_out[(size_t)rn*3+1], cdiff[ee][1] * we);
                    atomicAdd(&coord_out[(size_t)rn*3+2], cdiff[ee][2] * we);
                }
            }
        }
    }
}

// 512 threads = 8 waves. Reads the full 512B h_out row = [hB | agg] (bf16),
// then overwrites the row with final f32 h_out.
__global__ __launch_bounds__(512) void node_kernel(
    const float* __restrict__ h,
    const __bf16* __restrict__ nW1t, const float* __restrict__ nb1,
    const __bf16* __restrict__ nW2t, const float* __restrict__ nb2,
    float* __restrict__ h_out)
{
    __shared__ __align__(16) __bf16 featsN[TN2][264];
    __shared__ __align__(16) __bf16 hidN[TN2][136];

    const int t  = threadIdx.x;
    const int n0 = blockIdx.x * TN2;

    {
        const int n = t >> 3;
        const int q = t & 7;
        const int nid = n0 + n;
        const bool ok = nid < NN;
        const uint4* rowp = (const uint4*)((const char*)h_out + (size_t)nid * 512);
        #pragma unroll
        for (int j = 0; j < 4; j++) {
            const int w4 = q * 4 + j;
            uint4 u = ok ? rowp[w4] : make_uint4(0u, 0u, 0u, 0u);
            *(uint4*)&featsN[n][w4 * 8] = u;
        }
    }
    __syncthreads();

    const int wv2  = t >> 6;
    const int hh2  = wv2 >> 1;
    const int mh   = wv2 & 1;
    const int lane = t & 63;
    const int lr   = lane & 15;
    const int lg   = lane >> 4;

    const f32x4 z4 = { 0.f, 0.f, 0.f, 0.f };

    {
        f32x4 acc[2][2];
        #pragma unroll
        for (int mti = 0; mti < 2; mti++) { acc[mti][0] = z4; acc[mti][1] = z4; }
        const __bf16* W1 = nW1t + (size_t)hh2 * 32 * 256;
        #pragma unroll
        for (int ks = 0; ks < 8; ks++) {
            const int kof = ks * 32 + lg * 8;
            bf16x8 b0 = *(const bf16x8*)(W1 + (size_t)lr * 256 + kof);
            bf16x8 b1 = *(const bf16x8*)(W1 + (size_t)(16 + lr) * 256 + kof);
            #pragma unroll
            for (int mti = 0; mti < 2; mti++) {
                bf16x8 a = *(const bf16x8*)(&featsN[(mh * 2 + mti) * 16 + lr][kof]);
                acc[mti][0] = MFMA(a, b0, acc[mti][0]);
                acc[mti][1] = MFMA(a, b1, acc[mti][1]);
            }
        }
        const float b1a = nb1[hh2 * 32 + lr];
        const float b1b = nb1[hh2 * 32 + 16 + lr];
        #pragma unroll
        for (int mti = 0; mti < 2; mti++) {
            #pragma unroll
            for (int r = 0; r < 4; r++) {
                const int erow = (mh * 2 + mti) * 16 + lg * 4 + r;
                hidN[erow][hh2 * 32 + lr]      = fbf(silu_f(acc[mti][0][r] + b1a));
                hidN[erow][hh2 * 32 + 16 + lr] = fbf(silu_f(acc[mti][1][r] + b1b));
            }
        }
    }
    __syncthreads();

    {
        f32x4 acc2[2][2];
        #pragma unroll
        for (int mti = 0; mti < 2; mti++) { acc2[mti][0] = z4; acc2[mti][1] = z4; }
        const __bf16* W2 = nW2t + (size_t)hh2 * 32 * 128;
        #pragma unroll
        for (int ks = 0; ks < 4; ks++) {
            const int kof = ks * 32 + lg * 8;
            bf16x8 b0 = *(const bf16x8*)(W2 + (size_t)lr * 128 + kof);
            bf16x8 b1 = *(const bf16x8*)(W2 + (size_t)(16 + lr) * 128 + kof);
            #pragma unroll
            for (int mti = 0; mti < 2; mti++) {
                bf16x8 a = *(const bf16x8*)(&hidN[(mh * 2 + mti) * 16 + lr][kof]);
                acc2[mti][0] = MFMA(a, b0, acc2[mti][0]);
                acc2[mti][1] = MFMA(a, b1, acc2[mti][1]);
            }
        }
        const float b2a = nb2[hh2 * 32 + lr];
        const float b2b = nb2[hh2 * 32 + 16 + lr];
        const int c0 = hh2 * 32 + lr, c1 = c0 + 16;
        #pragma unroll
        for (int mti = 0; mti < 2; mti++) {
            #pragma unroll
            for (int r = 0; r < 4; r++) {
                const int erow = (mh * 2 + mti) * 16 + lg * 4 + r;
                const int nid  = n0 + erow;
                if (nid < NN) {
                    h_out[(size_t)nid * FIN + c0] = h[(size_t)nid * FIN + c0] + acc2[mti][0][r] + b2a;
                    h_out[(size_t)nid * FIN + c1] = h[(size_t)nid * FIN + c1] + acc2[mti][1][r] + b2b;
                }
            }
        }
    }
}

extern "C" void kernel_launch(void* const* d_in, const int* in_sizes, int n_in,
                              void* d_out, int out_size, void* d_ws, size_t ws_size,
                              hipStream_t stream)
{
    (void)in_sizes; (void)n_in; (void)out_size; (void)ws_size;
    const float* h     = (const float*)d_in[0];
    const float* coord = (const float*)d_in[1];
    const int*   ei    = (const int*)d_in[2];
    const float* eW1   = (const float*)d_in[3];
    const float* eb1   = (const float*)d_in[4];
    const float* eW2   = (const float*)d_in[5];
    const float* eb2   = (const float*)d_in[6];
    const float* ln_g  = (const float*)d_in[7];
    const float* ln_b  = (const float*)d_in[8];
    const float* nW1   = (const float*)d_in[9];
    const float* nb1   = (const float*)d_in[10];
    const float* nW2   = (const float*)d_in[11];
    const float* nb2   = (const float*)d_in[12];
    const float* cW1   = (const float*)d_in[13];
    const float* cb1   = (const float*)d_in[14];
    const float* cW2   = (const float*)d_in[15];

    float* h_out     = (float*)d_out;
    float* coord_out = h_out + (size_t)NN * FIN;

    __bf16* eW1t = (__bf16*)d_ws;
    __bf16* eW2t = eW1t + 4 * 32 * K1;
    __bf16* cW1t = eW2t + 4 * HD * HD;
    __bf16* nW1t = cW1t + HIDN * HIDN;
    __bf16* nW2t = nW1t + HIDN * (2 * FIN);

    hipMemsetAsync(h_out, 0, (size_t)NN * FIN * sizeof(float), stream);
    hipMemcpyAsync(coord_out, coord, (size_t)NN * 3 * sizeof(float),
                   hipMemcpyDeviceToDevice, stream);
    wconv_kernel<<<(4 * 32 * K1 + 255) / 256, 256, 0, stream>>>(
        eW1, eW2, cW1, nW1, nW2, eW1t, eW2t, cW1t, nW1t, nW2t);
    hconv_kernel<<<(NN * FIN / 8 + 255) / 256, 256, 0, stream>>>(h, h_out);

    edge_kernel<<<EE / TE, 256, 0, stream>>>(coord, ei, eW1t, eb1, eW2t, eb2,
                                             ln_g, ln_b, cW1t, cb1, cW2,
                                             h_out, coord_out);
    node_kernel<<<(NN + TN2 - 1) / TN2, 512, 0, stream>>>(h, nW1t, nb1, nW2t, nb2, h_out);
}

// Round 19
// 411.918 us; speedup vs baseline: 1.8673x; 1.8673x over previous
//
#include <hip/hip_runtime.h>
#include <hip/hip_bf16.h>
#include <math.h>

#define NN 50000
#define EE 800000
#define FIN 128
#define HIDN 128
#define HD 32
#define FEATD 268
#define K1 288           // GEMM1 K padded to 9*32
#define KP1 296          // featsB LDS row stride (bf16 elems)
#define TE 32
#define TN2 64

typedef __bf16 bf16x8 __attribute__((ext_vector_type(8)));
typedef float  f32x4  __attribute__((ext_vector_type(4)));

#define MFMA(a, b, c) __builtin_amdgcn_mfma_f32_16x16x32_bf16((a), (b), (c), 0, 0, 0)

__device__ __forceinline__ float silu_f(float x) {
    const float e = __builtin_amdgcn_exp2f(-1.44269504088896f * x);
    return x * __builtin_amdgcn_rcpf(1.0f + e);
}

__device__ __forceinline__ __bf16 fbf(float x) {
    union { float f; unsigned u; } v; v.f = x;
    const unsigned r = (v.u + 0x7FFFu + ((v.u >> 16) & 1u)) >> 16;
    union { unsigned short s; __bf16 b; } o; o.s = (unsigned short)r;
    return o.b;
}

// Transpose + bf16-convert all weights into ws each launch (deterministic).
__global__ void wconv_kernel(const float* __restrict__ eW1, const float* __restrict__ eW2,
                             const float* __restrict__ cW1, const float* __restrict__ nW1,
                             const float* __restrict__ nW2,
                             __bf16* __restrict__ eW1t, __bf16* __restrict__ eW2t,
                             __bf16* __restrict__ cW1t, __bf16* __restrict__ nW1t,
                             __bf16* __restrict__ nW2t)
{
    const int i = blockIdx.x * 256 + threadIdx.x;
    if (i < 4 * 32 * K1) {
        const int hh = i / (32 * K1), rs = i % (32 * K1), d = rs / K1, k = rs % K1;
        const float v = (k < FEATD) ? eW1[(size_t)hh * FEATD * HD + (size_t)k * HD + d] : 0.f;
        eW1t[i] = (__bf16)v;
    }
    if (i < 4 * HD * HD) {
        const int hh = i / (HD * HD), rs = i % (HD * HD), d = rs / HD, k = rs % HD;
        eW2t[i] = (__bf16)eW2[(size_t)hh * HD * HD + (size_t)k * HD + d];
    }
    if (i < HIDN * HIDN) {
        const int o = i / HIDN, k = i % HIDN;
        cW1t[i] = (__bf16)cW1[(size_t)k * HIDN + o];
    }
    if (i < HIDN * (2 * FIN)) {
        const int o = i / (2 * FIN), k = i % (2 * FIN);
        nW1t[i] = (__bf16)nW1[(size_t)k * HIDN + o];
    }
    if (i < FIN * HIDN) {
        const int o = i / HIDN, k = i % HIDN;
        nW2t[i] = (__bf16)nW2[(size_t)k * FIN + o];
    }
}

// Convert h (f32 [NN][128]) -> bf16 in the LOWER 256B of each 512B h_out row.
__global__ __launch_bounds__(256) void hconv_kernel(const float* __restrict__ h,
                                                    float* __restrict__ houtbase)
{
    const int i = blockIdx.x * 256 + threadIdx.x;
    if (i >= NN * FIN / 8) return;
    const int row = i >> 4;
    const int c8  = i & 15;
    const float4* src = (const float4*)(h + (size_t)row * FIN + c8 * 8);
    float4 a = src[0], b = src[1];
    bf16x8 v = { fbf(a.x), fbf(a.y), fbf(a.z), fbf(a.w),
                 fbf(b.x), fbf(b.y), fbf(b.z), fbf(b.w) };
    *(bf16x8*)((char*)houtbase + (size_t)row * 512 + c8 * 16) = v;
}

// TE=32, 256 threads = 4 waves (wave = head). 4 barriers per tile:
// stage | GEMM1+GEMM2(no bar, same-wave hidB) + lnS | LN-norm | agg-atomics + GEMM3 | coord.
__global__ __launch_bounds__(256) void edge_kernel(
    const float* __restrict__ coord,
    const int* __restrict__ ei,
    const __bf16* __restrict__ eW1t, const float* __restrict__ eb1,
    const __bf16* __restrict__ eW2t, const float* __restrict__ eb2,
    const float* __restrict__ ln_g, const float* __restrict__ ln_b,
    const __bf16* __restrict__ cW1t, const float* __restrict__ cb1,
    const float* __restrict__ cW2,
    float* __restrict__ houtbase, float* __restrict__ coord_out)
{
    __shared__ __align__(16) __bf16 featsB[TE][KP1];               // 18,944B (never aliased)
    __shared__ __align__(16) unsigned char smemB[4 * TE * 40 * 2]; // 10,240B: hidB -> efsB alias
    __shared__ float cdiff[TE][3];
    __shared__ int   rowlds[TE];
    __shared__ float wsum[TE];
    __shared__ float lnS[TE][2];

    __bf16 (*efsB)[136] = (__bf16 (*)[136])smemB;

    const int t  = threadIdx.x;
    const int e0 = blockIdx.x * TE;

    if (t < TE) { wsum[t] = 0.f; lnS[t][0] = 0.f; lnS[t][1] = 0.f; }

    // ---------------- Phase 0: gather hB (bf16) + geometry into featsB ----------------
    {
        const int e = t >> 3;        // edge 0..31 (8 threads/edge)
        const int q = t & 7;
        const int r = ei[e0 + e];
        const int c = ei[EE + e0 + e];
        #pragma unroll
        for (int j = 0; j < 2; j++) {
            const int c16 = q + 8 * j;   // 16B-chunk index 0..15
            uint4 vr = *(const uint4*)((const char*)houtbase + (size_t)r * 512 + c16 * 16);
            *(uint4*)&featsB[e][c16 * 8] = vr;
            uint4 vc = *(const uint4*)((const char*)houtbase + (size_t)c * 512 + c16 * 16);
            *(uint4*)&featsB[e][FIN + c16 * 8] = vc;
        }
        if (q == 0) {
            rowlds[e] = r;
            const float cix = coord[(size_t)r*3+0], ciy = coord[(size_t)r*3+1], ciz = coord[(size_t)r*3+2];
            const float ckx = coord[(size_t)c*3+0], cky = coord[(size_t)c*3+1], ckz = coord[(size_t)c*3+2];
            const float dx = cix-ckx, dy = ciy-cky, dz = ciz-ckz;
            cdiff[e][0]=dx; cdiff[e][1]=dy; cdiff[e][2]=dz;
            const float radial = dx*dx + dy*dy + dz*dz;
            const float dist   = sqrtf(radial);
            const float dotv   = cix*ckx + ciy*cky + ciz*ckz;
            const float ia = 1.0f / (dist + 1e-8f);
            float ax = dx*ia, ay = dy*ia, az = dz*ia;
            const float cpx = ciy*ckz - ciz*cky;
            const float cpy = ciz*ckx - cix*ckz;
            const float cpz = cix*cky - ciy*ckx;
            const float cpn = sqrtf(cpx*cpx + cpy*cpy + cpz*cpz);
            const float ib = 1.0f / (cpn + 1e-8f);
            float bx = cpx*ib, by = cpy*ib, bz = cpz*ib;
            float cx = ay*bz - az*by;
            float cy = az*bx - ax*bz;
            float cz = ax*by - ay*bx;
            const float na = sqrtf(ax*ax + ay*ay + az*az);
            const float nb = sqrtf(bx*bx + by*by + bz*bz);
            const float nc = sqrtf(cx*cx + cy*cy + cz*cz);
            if (na < 1e-6f || nb < 1e-6f || nc < 1e-6f) {
                ax=1.f; bx=0.f; cx=0.f;
                ay=0.f; by=1.f; cy=0.f;
                az=0.f; bz=0.f; cz=1.f;
            }
            featsB[e][256]=fbf(radial); featsB[e][257]=fbf(dist); featsB[e][258]=fbf(dotv);
            featsB[e][259]=fbf(ax); featsB[e][260]=fbf(bx); featsB[e][261]=fbf(cx);
            featsB[e][262]=fbf(ay); featsB[e][263]=fbf(by); featsB[e][264]=fbf(cy);
            featsB[e][265]=fbf(az); featsB[e][266]=fbf(bz); featsB[e][267]=fbf(cz);
            #pragma unroll
            for (int k = FEATD; k < K1; k++) featsB[e][k] = (__bf16)0.f;
        }
    }
    __syncthreads();   // BAR1: featsB + init ready

    const int hh   = t >> 6;          // wave = head
    const int lane = t & 63;
    const int lr   = lane & 15;
    const int lg   = lane >> 4;
    __bf16* hidB = ((__bf16*)smemB) + hh * (TE * 40);

    const f32x4 z4 = { 0.f, 0.f, 0.f, 0.f };

    // ---------------- GEMM1 -> hidB (same wave) -> GEMM2 -> val regs + lnS ----------------
    float val[2][2][4];
    {
        f32x4 acc[2][2];
        #pragma unroll
        for (int mti = 0; mti < 2; mti++) { acc[mti][0] = z4; acc[mti][1] = z4; }
        const __bf16* W1 = eW1t + (size_t)hh * 32 * K1;
        #pragma unroll
        for (int ks = 0; ks < 9; ks++) {
            const int kof = ks * 32 + lg * 8;
            bf16x8 b0 = *(const bf16x8*)(W1 + (size_t)lr * K1 + kof);
            bf16x8 b1 = *(const bf16x8*)(W1 + (size_t)(16 + lr) * K1 + kof);
            #pragma unroll
            for (int mti = 0; mti < 2; mti++) {
                bf16x8 a = *(const bf16x8*)(&featsB[mti * 16 + lr][kof]);
                acc[mti][0] = MFMA(a, b0, acc[mti][0]);
                acc[mti][1] = MFMA(a, b1, acc[mti][1]);
            }
        }
        const float b1a = eb1[hh * HD + lr];
        const float b1b = eb1[hh * HD + 16 + lr];
        #pragma unroll
        for (int mti = 0; mti < 2; mti++) {
            #pragma unroll
            for (int r = 0; r < 4; r++) {
                const int erow = mti * 16 + lg * 4 + r;
                hidB[erow * 40 + lr]      = fbf(silu_f(acc[mti][0][r] + b1a));
                hidB[erow * 40 + 16 + lr] = fbf(silu_f(acc[mti][1][r] + b1b));
            }
        }
        // GEMM2 reads hidB written by the SAME wave -> compiler lgkmcnt, no barrier.
        f32x4 acc2[2][2];
        #pragma unroll
        for (int mti = 0; mti < 2; mti++) { acc2[mti][0] = z4; acc2[mti][1] = z4; }
        const __bf16* W2 = eW2t + (size_t)hh * HD * HD;
        const int kof2 = lg * 8;
        bf16x8 b20 = *(const bf16x8*)(W2 + (size_t)lr * HD + kof2);
        bf16x8 b21 = *(const bf16x8*)(W2 + (size_t)(16 + lr) * HD + kof2);
        #pragma unroll
        for (int mti = 0; mti < 2; mti++) {
            bf16x8 a = *(const bf16x8*)(hidB + (mti * 16 + lr) * 40 + kof2);
            acc2[mti][0] = MFMA(a, b20, acc2[mti][0]);
            acc2[mti][1] = MFMA(a, b21, acc2[mti][1]);
        }
        const float b2a = eb2[hh * HD + lr];
        const float b2b = eb2[hh * HD + 16 + lr];
        #pragma unroll
        for (int mti = 0; mti < 2; mti++) {
            #pragma unroll
            for (int r = 0; r < 4; r++) {
                val[mti][0][r] = acc2[mti][0][r] + b2a;
                val[mti][1][r] = acc2[mti][1][r] + b2b;
                float s  = val[mti][0][r] + val[mti][1][r];
                float s2 = val[mti][0][r]*val[mti][0][r] + val[mti][1][r]*val[mti][1][r];
                s  += __shfl_xor(s, 1);  s2 += __shfl_xor(s2, 1);
                s  += __shfl_xor(s, 2);  s2 += __shfl_xor(s2, 2);
                s  += __shfl_xor(s, 4);  s2 += __shfl_xor(s2, 4);
                s  += __shfl_xor(s, 8);  s2 += __shfl_xor(s2, 8);
                if (lr == 0) {
                    const int R = mti * 16 + lg * 4 + r;
                    atomicAdd(&lnS[R][0], s);
                    atomicAdd(&lnS[R][1], s2);
                }
            }
        }
    }
    __syncthreads();   // BAR2: lnS complete; all hidB reads done (efsB alias safe)

    // ---------------- LN normalize in registers -> efsB ----------------
    {
        const int c0 = hh * 32 + lr, c1 = c0 + 16;
        const float g0 = ln_g[c0], bl0 = ln_b[c0];
        const float g1 = ln_g[c1], bl1 = ln_b[c1];
        #pragma unroll
        for (int mti = 0; mti < 2; mti++) {
            #pragma unroll
            for (int r = 0; r < 4; r++) {
                const int R = mti * 16 + lg * 4 + r;
                const float mu   = lnS[R][0] * (1.f / 128.f);
                const float var  = lnS[R][1] * (1.f / 128.f) - mu * mu;
                const float rstd = rsqrtf(var + 1e-5f);
                efsB[R][c0] = fbf((val[mti][0][r] - mu) * rstd * g0 + bl0);
                efsB[R][c1] = fbf((val[mti][1][r] - mu) * rstd * g1 + bl1);
            }
        }
    }
    __syncthreads();   // BAR3: efsB ready (cross-wave)

    // ---------------- agg scatter FIRST (atomics overlap GEMM3) ----------------
    {
        const int p  = t & 63;
        const int gq = t >> 6;
        #pragma unroll
        for (int e2 = 0; e2 < 8; e2++) {
            const int ee = gq * 8 + e2;
            __hip_bfloat162 pk = *(__hip_bfloat162*)&efsB[ee][2 * p];
            __hip_bfloat162* addr = (__hip_bfloat162*)
                ((char*)houtbase + (size_t)rowlds[ee] * 512 + 256 + p * 4);
            unsafeAtomicAdd(addr, pk);
        }
    }

    // ---------------- GEMM3: efsB @ cW1t^T -> silu -> *cW2 -> w ----------------
    {
        f32x4 acc3[2][2];
        #pragma unroll
        for (int mti = 0; mti < 2; mti++) { acc3[mti][0] = z4; acc3[mti][1] = z4; }
        const __bf16* W3 = cW1t + (size_t)hh * 32 * HIDN;
        #pragma unroll
        for (int ks = 0; ks < 4; ks++) {
            const int kof = ks * 32 + lg * 8;
            bf16x8 b30 = *(const bf16x8*)(W3 + (size_t)lr * HIDN + kof);
            bf16x8 b31 = *(const bf16x8*)(W3 + (size_t)(16 + lr) * HIDN + kof);
            #pragma unroll
            for (int mti = 0; mti < 2; mti++) {
                bf16x8 a = *(const bf16x8*)(&efsB[mti * 16 + lr][kof]);
                acc3[mti][0] = MFMA(a, b30, acc3[mti][0]);
                acc3[mti][1] = MFMA(a, b31, acc3[mti][1]);
            }
        }
        const int c0 = hh * 32 + lr, c1 = c0 + 16;
        const float cbA = cb1[c0], cbB = cb1[c1];
        const float cwA = cW2[c0], cwB = cW2[c1];
        float pe[8];
        #pragma unroll
        for (int mti = 0; mti < 2; mti++)
            #pragma unroll
            for (int r = 0; r < 4; r++)
                pe[mti * 4 + r] = silu_f(acc3[mti][0][r] + cbA) * cwA
                                + silu_f(acc3[mti][1][r] + cbB) * cwB;
        #pragma unroll
        for (int d = 1; d < 16; d <<= 1)
            #pragma unroll
            for (int i = 0; i < 8; i++) pe[i] += __shfl_xor(pe[i], d);
        if (lr == 0) {
            #pragma unroll
            for (int mti = 0; mti < 2; mti++)
                #pragma unroll
                for (int r = 0; r < 4; r++)
                    atomicAdd(&wsum[mti * 16 + lg * 4 + r], pe[mti * 4 + r]);
        }
    }
    __syncthreads();   // BAR4: wsum ready

    // ---------------- coord scatter ----------------
    if (t < TE) {
        const float we = wsum[t];
        const int r = rowlds[t];
        atomicAdd(&coord_out[(size_t)r*3+0], cdiff[t][0] * we);
        atomicAdd(&coord_out[(size_t)r*3+1], cdiff[t][1] * we);
        atomicAdd(&coord_out[(size_t)r*3+2], cdiff[t][2] * we);
    }
}

// 512 threads = 8 waves. Reads the full 512B h_out row = [hB | agg] (bf16),
// then overwrites the row with final f32 h_out.
__global__ __launch_bounds__(512) void node_kernel(
    const float* __restrict__ h,
    const __bf16* __restrict__ nW1t, const float* __restrict__ nb1,
    const __bf16* __restrict__ nW2t, const float* __restrict__ nb2,
    float* __restrict__ h_out)
{
    __shared__ __align__(16) __bf16 featsN[TN2][264];
    __shared__ __align__(16) __bf16 hidN[TN2][136];

    const int t  = threadIdx.x;
    const int n0 = blockIdx.x * TN2;

    {
        const int n = t >> 3;
        const int q = t & 7;
        const int nid = n0 + n;
        const bool ok = nid < NN;
        const uint4* rowp = (const uint4*)((const char*)h_out + (size_t)nid * 512);
        #pragma unroll
        for (int j = 0; j < 4; j++) {
            const int w4 = q * 4 + j;
            uint4 u = ok ? rowp[w4] : make_uint4(0u, 0u, 0u, 0u);
            *(uint4*)&featsN[n][w4 * 8] = u;
        }
    }
    __syncthreads();

    const int wv2  = t >> 6;
    const int hh2  = wv2 >> 1;
    const int mh   = wv2 & 1;
    const int lane = t & 63;
    const int lr   = lane & 15;
    const int lg   = lane >> 4;

    const f32x4 z4 = { 0.f, 0.f, 0.f, 0.f };

    {
        f32x4 acc[2][2];
        #pragma unroll
        for (int mti = 0; mti < 2; mti++) { acc[mti][0] = z4; acc[mti][1] = z4; }
        const __bf16* W1 = nW1t + (size_t)hh2 * 32 * 256;
        #pragma unroll
        for (int ks = 0; ks < 8; ks++) {
            const int kof = ks * 32 + lg * 8;
            bf16x8 b0 = *(const bf16x8*)(W1 + (size_t)lr * 256 + kof);
            bf16x8 b1 = *(const bf16x8*)(W1 + (size_t)(16 + lr) * 256 + kof);
            #pragma unroll
            for (int mti = 0; mti < 2; mti++) {
                bf16x8 a = *(const bf16x8*)(&featsN[(mh * 2 + mti) * 16 + lr][kof]);
                acc[mti][0] = MFMA(a, b0, acc[mti][0]);
                acc[mti][1] = MFMA(a, b1, acc[mti][1]);
            }
        }
        const float b1a = nb1[hh2 * 32 + lr];
        const float b1b = nb1[hh2 * 32 + 16 + lr];
        #pragma unroll
        for (int mti = 0; mti < 2; mti++) {
            #pragma unroll
            for (int r = 0; r < 4; r++) {
                const int erow = (mh * 2 + mti) * 16 + lg * 4 + r;
                hidN[erow][hh2 * 32 + lr]      = fbf(silu_f(acc[mti][0][r] + b1a));
                hidN[erow][hh2 * 32 + 16 + lr] = fbf(silu_f(acc[mti][1][r] + b1b));
            }
        }
    }
    __syncthreads();

    {
        f32x4 acc2[2][2];
        #pragma unroll
        for (int mti = 0; mti < 2; mti++) { acc2[mti][0] = z4; acc2[mti][1] = z4; }
        const __bf16* W2 = nW2t + (size_t)hh2 * 32 * 128;
        #pragma unroll
        for (int ks = 0; ks < 4; ks++) {
            const int kof = ks * 32 + lg * 8;
            bf16x8 b0 = *(const bf16x8*)(W2 + (size_t)lr * 128 + kof);
            bf16x8 b1 = *(const bf16x8*)(W2 + (size_t)(16 + lr) * 128 + kof);
            #pragma unroll
            for (int mti = 0; mti < 2; mti++) {
                bf16x8 a = *(const bf16x8*)(&hidN[(mh * 2 + mti) * 16 + lr][kof]);
                acc2[mti][0] = MFMA(a, b0, acc2[mti][0]);
                acc2[mti][1] = MFMA(a, b1, acc2[mti][1]);
            }
        }
        const float b2a = nb2[hh2 * 32 + lr];
        const float b2b = nb2[hh2 * 32 + 16 + lr];
        const int c0 = hh2 * 32 + lr, c1 = c0 + 16;
        #pragma unroll
        for (int mti = 0; mti < 2; mti++) {
            #pragma unroll
            for (int r = 0; r < 4; r++) {
                const int erow = (mh * 2 + mti) * 16 + lg * 4 + r;
                const int nid  = n0 + erow;
                if (nid < NN) {
                    h_out[(size_t)nid * FIN + c0] = h[(size_t)nid * FIN + c0] + acc2[mti][0][r] + b2a;
                    h_out[(size_t)nid * FIN + c1] = h[(size_t)nid * FIN + c1] + acc2[mti][1][r] + b2b;
                }
            }
        }
    }
}

extern "C" void kernel_launch(void* const* d_in, const int* in_sizes, int n_in,
                              void* d_out, int out_size, void* d_ws, size_t ws_size,
                              hipStream_t stream)
{
    (void)in_sizes; (void)n_in; (void)out_size; (void)ws_size;
    const float* h     = (const float*)d_in[0];
    const float* coord = (const float*)d_in[1];
    const int*   ei    = (const int*)d_in[2];
    const float* eW1   = (const float*)d_in[3];
    const float* eb1   = (const float*)d_in[4];
    const float* eW2   = (const float*)d_in[5];
    const float* eb2   = (const float*)d_in[6];
    const float* ln_g  = (const float*)d_in[7];
    const float* ln_b  = (const float*)d_in[8];
    const float* nW1   = (const float*)d_in[9];
    const float* nb1   = (const float*)d_in[10];
    const float* nW2   = (const float*)d_in[11];
    const float* nb2   = (const float*)d_in[12];
    const float* cW1   = (const float*)d_in[13];
    const float* cb1   = (const float*)d_in[14];
    const float* cW2   = (const float*)d_in[15];

    float* h_out     = (float*)d_out;
    float* coord_out = h_out + (size_t)NN * FIN;

    __bf16* eW1t = (__bf16*)d_ws;
    __bf16* eW2t = eW1t + 4 * 32 * K1;
    __bf16* cW1t = eW2t + 4 * HD * HD;
    __bf16* nW1t = cW1t + HIDN * HIDN;
    __bf16* nW2t = nW1t + HIDN * (2 * FIN);

    hipMemsetAsync(h_out, 0, (size_t)NN * FIN * sizeof(float), stream);
    hipMemcpyAsync(coord_out, coord, (size_t)NN * 3 * sizeof(float),
                   hipMemcpyDeviceToDevice, stream);
    wconv_kernel<<<(4 * 32 * K1 + 255) / 256, 256, 0, stream>>>(
        eW1, eW2, cW1, nW1, nW2, eW1t, eW2t, cW1t, nW1t, nW2t);
    hconv_kernel<<<(NN * FIN / 8 + 255) / 256, 256, 0, stream>>>(h, h_out);

    edge_kernel<<<EE / TE, 256, 0, stream>>>(coord, ei, eW1t, eb1, eW2t, eb2,
                                             ln_g, ln_b, cW1t, cb1, cW2,
                                             h_out, coord_out);
    node_kernel<<<(NN + TN2 - 1) / TN2, 512, 0, stream>>>(h, nW1t, nb1, nW2t, nb2, h_out);
}